// Round 3
// baseline (228.763 us; speedup 1.0000x reference)
//
#include <hip/hip_runtime.h>
#include <hip/hip_bf16.h>

// ---------------------------------------------------------------------------
// SelfAttention2: out = x + sigma * proj(softmax(theta^T phi) applied to g)
//   x [8,256,64,64] fp32 ; inner dim 32 ; N = 4096
// Strategy: flash attention, head-dim 32, via mfma_f32_16x16x32_bf16.
//   K1 prep:  weights fp32 -> bf16 (W [96][256], Wa [256][32])
//   K2 proj:  QK [b][n][64] bf16 (Q cols 0-31, K cols 32-63), VT [b][32][n] bf16
//   K3 attn:  S^T = mfma(Kfrag, Qfrag); unnormalized exp (S bounded: no max
//             tracking needed); P via wave-private LDS; PV; fused W_attn
//             epilogue with coalesced out writes. No __syncthreads in K3.
// R2 fix: __hip_bfloat162 is not trivially copyable -> __builtin_bit_cast
//   failed to compile. pack_bf2 now packs two manual-RNE results via integer
//   ops (compiler pattern-matches the RNE sequence to v_cvt_pk_bf16_f32 per
//   learn_hip m240; hand asm not needed). LDS 16B-alignment fixes kept.
// ---------------------------------------------------------------------------

using f32x4  = __attribute__((ext_vector_type(4))) float;
using bf16x8 = __attribute__((ext_vector_type(8))) short;   // 8 bf16 in 4 VGPRs

#define NB   8
#define CIN  256
#define KD   32
#define NN   4096

// ws layout (bf16/short elements)
#define QK_OFF   0                            // [8][4096][64]
#define VT_OFF   (NB * NN * 64)               // [8][32][4096]
#define WB_OFF   (VT_OFF + NB * KD * NN)      // [96][256]
#define WAB_OFF  (WB_OFF + 96 * 256)          // [256][32]
#define WS_ELEMS (WAB_OFF + 256 * 32)

__device__ __forceinline__ short f2bf(float f) {
    unsigned u = __builtin_bit_cast(unsigned, f);
    u += 0x7fffu + ((u >> 16) & 1u);          // RNE (inputs finite)
    return (short)(u >> 16);
}

// two f32 -> packed bf16x2 in a u32 (low = a, high = b)
__device__ __forceinline__ unsigned pack_bf2(float a, float b) {
    return (unsigned)(unsigned short)f2bf(a) |
           ((unsigned)(unsigned short)f2bf(b) << 16);
}

// --------------------------- K1: weight prep -------------------------------
__global__ __launch_bounds__(256) void prep_kernel(
    const float* __restrict__ wt, const float* __restrict__ wp,
    const float* __restrict__ wg, const float* __restrict__ wa,
    short* __restrict__ ws)
{
    int t = blockIdx.x * 256 + threadIdx.x;   // grid covers exactly 24576+8192
    if (t < 96 * 256) {
        float v = (t < 32 * 256) ? wt[t]
                : (t < 64 * 256) ? wp[t - 32 * 256]
                                 : wg[t - 64 * 256];
        ws[WB_OFF + t] = f2bf(v);
    } else {
        int t2 = t - 96 * 256;
        ws[WAB_OFF + t2] = f2bf(wa[t2]);
    }
}

// --------------------------- K2: projections -------------------------------
// Per block: one batch, 64 n-columns, all 96 outputs. x tile transposed to
// LDS bf16; D[n][kout] = xT[n][c] * W^T[c][kout] via MFMA.
#define CSTR 264   // xT row stride (elements); 528B: b128-aligned, ~2-way banks

__global__ __launch_bounds__(256, 4) void proj_kernel(
    const float* __restrict__ x,
    const float* __restrict__ bt, const float* __restrict__ bp,
    const float* __restrict__ bg,
    short* __restrict__ ws)
{
    __shared__ __attribute__((aligned(16))) short xT[64 * CSTR];
    __shared__ __attribute__((aligned(16))) short vtl[KD * 72];

    const int b   = blockIdx.y;
    const int n0  = blockIdx.x * 64;
    const int tid = threadIdx.x;

    // stage x[256 c][64 n] -> xT bf16 (transposed), coalesced float4 reads
    {
        const int nq = (tid & 15) * 4;
        const int cb = tid >> 4;
        for (int cc = 0; cc < CIN; cc += 16) {
            const int c = cc + cb;
            const float4 v = *reinterpret_cast<const float4*>(
                x + (size_t)(b * CIN + c) * NN + n0 + nq);
            xT[(nq + 0) * CSTR + c] = f2bf(v.x);
            xT[(nq + 1) * CSTR + c] = f2bf(v.y);
            xT[(nq + 2) * CSTR + c] = f2bf(v.z);
            xT[(nq + 3) * CSTR + c] = f2bf(v.w);
        }
    }
    __syncthreads();

    const int lane = tid & 63;
    const int wv   = tid >> 6;       // 0..3, wave owns n rows wv*16..+15
    const int cL   = lane & 15;
    const int g    = lane >> 4;

    f32x4 acc[6];
    #pragma unroll
    for (int kt = 0; kt < 6; ++kt) acc[kt] = f32x4{0.f, 0.f, 0.f, 0.f};

    const short* Wb = ws + WB_OFF;
    #pragma unroll
    for (int kc = 0; kc < 8; ++kc) {
        bf16x8 a = *reinterpret_cast<const bf16x8*>(
            &xT[(wv * 16 + cL) * CSTR + kc * 32 + g * 8]);
        #pragma unroll
        for (int kt = 0; kt < 6; ++kt) {
            bf16x8 bb = *reinterpret_cast<const bf16x8*>(
                Wb + (kt * 16 + cL) * 256 + kc * 32 + g * 8);
            acc[kt] = __builtin_amdgcn_mfma_f32_16x16x32_bf16(a, bb, acc[kt], 0, 0, 0);
        }
    }

    // Q (kt 0,1) and K (kt 2,3) -> QK [n][64]
    short* QK = ws + QK_OFF;
    #pragma unroll
    for (int kt = 0; kt < 4; ++kt) {
        const float bias = (kt < 2) ? bt[kt * 16 + cL] : bp[(kt - 2) * 16 + cL];
        #pragma unroll
        for (int r = 0; r < 4; ++r) {
            const int n = n0 + wv * 16 + 4 * g + r;
            QK[(size_t)(b * NN + n) * 64 + kt * 16 + cL] = f2bf(acc[kt][r] + bias);
        }
    }
    // V (kt 4,5) -> LDS transpose -> VT [32][n] (coalesced global write)
    #pragma unroll
    for (int kt = 4; kt < 6; ++kt) {
        const float bias = bg[(kt - 4) * 16 + cL];
        const int d = (kt - 4) * 16 + cL;
        unsigned lo = pack_bf2(acc[kt][0] + bias, acc[kt][1] + bias);
        unsigned hi = pack_bf2(acc[kt][2] + bias, acc[kt][3] + bias);
        *reinterpret_cast<uint2*>(&vtl[d * 72 + wv * 16 + 4 * g]) = make_uint2(lo, hi);
    }
    __syncthreads();
    {
        short* VT = ws + VT_OFF;
        const int d  = tid >> 3;
        const int nn = (tid & 7) * 8;
        bf16x8 v = *reinterpret_cast<const bf16x8*>(&vtl[d * 72 + nn]);
        *reinterpret_cast<bf16x8*>(&VT[(size_t)(b * KD + d) * NN + n0 + nn]) = v;
    }
}

// --------------------------- K3: flash attention + epilogue ----------------
// 512 threads = 8 waves; wave owns 16 Q-rows (i = i0 + wv*16 + (lane&15)).
// All LDS is wave-private -> no __syncthreads anywhere.
#define PSTR 72    // P row stride (elems); 144B: b128-aligned
#define OSTR 40    // O row stride; 80B: b128-aligned

__global__ __launch_bounds__(512, 2) void attn_kernel(
    const float* __restrict__ x,
    const float* __restrict__ ba,
    const float* __restrict__ sigma_p,
    const short* __restrict__ ws,
    float* __restrict__ out)
{
    __shared__ __attribute__((aligned(16))) short P [8 * 16 * PSTR];
    __shared__ __attribute__((aligned(16))) short OL[8 * 16 * OSTR];
    __shared__ __attribute__((aligned(16))) float LB[8 * 16];

    const int b    = blockIdx.y;
    const int i0   = blockIdx.x * 128;
    const int tid  = threadIdx.x;
    const int wv   = tid >> 6;
    const int lane = tid & 63;
    const int cL   = lane & 15;
    const int g    = lane >> 4;

    const short* QK = ws + QK_OFF + (size_t)b * NN * 64;
    const short* VT = ws + VT_OFF + (size_t)b * KD * NN;
    short* Pw = P  + wv * 16 * PSTR;
    short* Ow = OL + wv * 16 * OSTR;

    const int iw = i0 + wv * 16;
    // Q as B-operand: B[k][i=cL] = Q[iw+cL][k], contiguous 16B
    bf16x8 qf = *reinterpret_cast<const bf16x8*>(&QK[(iw + cL) * 64 + g * 8]);

    const f32x4 zero = f32x4{0.f, 0.f, 0.f, 0.f};
    f32x4 o0 = zero, o1 = zero;
    float lsum = 0.f;

    for (int j0 = 0; j0 < NN; j0 += 64) {
        // S^T[j][i] = K_tile * Q^T  (A-frag = K rows j, row index = cL)
        f32x4 s[4];
        #pragma unroll
        for (int jf = 0; jf < 4; ++jf) {
            bf16x8 kf = *reinterpret_cast<const bf16x8*>(
                &QK[(j0 + jf * 16 + cL) * 64 + 32 + g * 8]);
            s[jf] = __builtin_amdgcn_mfma_f32_16x16x32_bf16(kf, qf, zero, 0, 0, 0);
        }
        // unnormalized exp; pack 4 consecutive j per lane -> one b64 LDS write
        #pragma unroll
        for (int jf = 0; jf < 4; ++jf) {
            float p0 = __expf(s[jf][0]);
            float p1 = __expf(s[jf][1]);
            float p2 = __expf(s[jf][2]);
            float p3 = __expf(s[jf][3]);
            lsum += (p0 + p1) + (p2 + p3);
            unsigned lo = pack_bf2(p0, p1);
            unsigned hi = pack_bf2(p2, p3);
            *reinterpret_cast<uint2*>(&Pw[cL * PSTR + jf * 16 + 4 * g]) =
                make_uint2(lo, hi);
        }
        // PV: O[i][d] += P[i][j] V[j][d]; P A-frag from LDS, V B-frag from VT
        #pragma unroll
        for (int jc = 0; jc < 2; ++jc) {
            bf16x8 pa = *reinterpret_cast<const bf16x8*>(
                &Pw[cL * PSTR + jc * 32 + g * 8]);
            bf16x8 v0 = *reinterpret_cast<const bf16x8*>(
                &VT[(size_t)(0 * 16 + cL) * NN + j0 + jc * 32 + g * 8]);
            bf16x8 v1 = *reinterpret_cast<const bf16x8*>(
                &VT[(size_t)(1 * 16 + cL) * NN + j0 + jc * 32 + g * 8]);
            o0 = __builtin_amdgcn_mfma_f32_16x16x32_bf16(pa, v0, o0, 0, 0, 0);
            o1 = __builtin_amdgcn_mfma_f32_16x16x32_bf16(pa, v1, o1, 0, 0, 0);
        }
    }

    // row sums: reduce over lane groups (bits 4,5)
    lsum += __shfl_xor(lsum, 16, 64);
    lsum += __shfl_xor(lsum, 32, 64);
    if (g == 0) LB[wv * 16 + cL] = 1.0f / lsum;    // lane cL holds l[i=cL]
    float4 rl4 = *reinterpret_cast<const float4*>(&LB[wv * 16 + 4 * g]);
    const float rlv[4] = {rl4.x, rl4.y, rl4.z, rl4.w};

    // normalized O -> LDS [i][d] (scalar b16 writes, once per block)
    #pragma unroll
    for (int r = 0; r < 4; ++r) {
        Ow[(4 * g + r) * OSTR +  0 + cL] = f2bf(o0[r] * rlv[r]);
        Ow[(4 * g + r) * OSTR + 16 + cL] = f2bf(o1[r] * rlv[r]);
    }
    // B-operand for epilogue: B[d][i=cL] = O[cL][d], contiguous 16B
    bf16x8 ob = *reinterpret_cast<const bf16x8*>(&Ow[cL * OSTR + g * 8]);

    // epilogue: out^T[c][i] = Wa[c][d] * O^T[d][i]; out = x + sigma*(. + ba)
    const float sig = sigma_p[0];
    const short* Wab = ws + WAB_OFF;
    const int nidx = iw + cL;
    #pragma unroll 4
    for (int ct = 0; ct < 16; ++ct) {
        bf16x8 wf = *reinterpret_cast<const bf16x8*>(
            &Wab[(ct * 16 + cL) * KD + g * 8]);
        f32x4 d = __builtin_amdgcn_mfma_f32_16x16x32_bf16(wf, ob, zero, 0, 0, 0);
        #pragma unroll
        for (int r = 0; r < 4; ++r) {
            const int c = ct * 16 + 4 * g + r;
            const size_t idx = (size_t)(b * CIN + c) * NN + nidx;
            out[idx] = x[idx] + sig * (d[r] + ba[c]);   // 16 lanes: 64B coalesced
        }
    }
}

// ---------------------------------------------------------------------------
extern "C" void kernel_launch(void* const* d_in, const int* in_sizes, int n_in,
                              void* d_out, int out_size, void* d_ws, size_t ws_size,
                              hipStream_t stream)
{
    const float* x  = (const float*)d_in[0];
    const float* wt = (const float*)d_in[1];
    const float* bt = (const float*)d_in[2];
    const float* wp = (const float*)d_in[3];
    const float* bp = (const float*)d_in[4];
    const float* wg = (const float*)d_in[5];
    const float* bg = (const float*)d_in[6];
    const float* wa = (const float*)d_in[7];
    const float* ba = (const float*)d_in[8];
    const float* sg = (const float*)d_in[9];
    short* ws  = (short*)d_ws;
    float* out = (float*)d_out;

    if (ws_size < (size_t)WS_ELEMS * sizeof(short)) return;  // ~6.4 MB needed

    hipLaunchKernelGGL(prep_kernel, dim3(128),     dim3(256), 0, stream,
                       wt, wp, wg, wa, ws);
    hipLaunchKernelGGL(proj_kernel, dim3(64, NB),  dim3(256), 0, stream,
                       x, bt, bp, bg, ws);
    hipLaunchKernelGGL(attn_kernel, dim3(32, NB),  dim3(512), 0, stream,
                       x, ba, sg, ws, out);
}